// Round 3
// baseline (545.691 us; speedup 1.0000x reference)
//
#include <hip/hip_runtime.h>
#include <hip/hip_bf16.h>
#include <math.h>

#define SEQ   2048
#define EMBED 2048
#define NHEAD 16
#define DHEAD 128
#define BATCH 2

#define NX   ((size_t)BATCH * SEQ * EMBED)   // 8388608
#define NW1  ((size_t)3 * EMBED * EMBED)     // 12582912
#define NB1  ((size_t)3 * EMBED)             // 6144
#define NW2  ((size_t)EMBED * EMBED)         // 4194304
#define NB2  ((size_t)EMBED)                 // 2048

typedef __bf16 bf16;
typedef __attribute__((__ext_vector_type__(8))) __bf16 bf16x8;
typedef __attribute__((__ext_vector_type__(4))) float f32x4;

#define NEG_BIG (-1.0e30f)

__device__ __forceinline__ f32x4 mfma_16x16x32(bf16x8 a, bf16x8 b, f32x4 c) {
  return __builtin_amdgcn_mfma_f32_16x16x32_bf16(a, b, c, 0, 0, 0);
}

// ---------------------------------------------------------------------------
// Dtype-agnostic input normalization. Detects whether inputs are stored as
// fp32 or bf16 (reading fp32 data as bf16 halfwords yields ~45% |v|>1e4 from
// random mantissa-derived exponents; true bf16 N(0,1) never exceeds ~6),
// then converts all five inputs into bf16 workspace buffers.
// ---------------------------------------------------------------------------
__global__ void convert_inputs(const void* __restrict__ xin,
                               const void* __restrict__ w1in,
                               const void* __restrict__ b1in,
                               const void* __restrict__ w2in,
                               const void* __restrict__ b2in,
                               bf16* __restrict__ xb, bf16* __restrict__ w1b,
                               bf16* __restrict__ b1b, bf16* __restrict__ w2b,
                               bf16* __restrict__ b2b, int* __restrict__ flagp)
{
  __shared__ int sflag;
  if (threadIdx.x == 0) sflag = 0;
  __syncthreads();
  const unsigned short* xh = (const unsigned short*)xin;
  int huge = 0;
  for (int i = threadIdx.x; i < 2048; i += 256) {
    float f = __uint_as_float((unsigned int)xh[i] << 16);
    if (!(fabsf(f) <= 1e4f)) huge = 1;  // catches NaN/Inf too
  }
  if (huge) sflag = 1;  // benign race, same value
  __syncthreads();
  const int isf32 = sflag;
  if (blockIdx.x == 0 && threadIdx.x == 0) *flagp = isf32;

  const size_t total = NX + NW1 + NB1 + NW2 + NB2;
  const size_t stride = (size_t)gridDim.x * blockDim.x;
  for (size_t i = (size_t)blockIdx.x * blockDim.x + threadIdx.x; i < total;
       i += stride) {
    const void* s; bf16* d; size_t off;
    if (i < NX)                      { s = xin;  d = xb;  off = i; }
    else if (i < NX + NW1)           { s = w1in; d = w1b; off = i - NX; }
    else if (i < NX + NW1 + NB1)     { s = b1in; d = b1b; off = i - NX - NW1; }
    else if (i < NX + NW1 + NB1 + NW2) {
      s = w2in; d = w2b; off = i - NX - NW1 - NB1;
    } else                           { s = b2in; d = b2b;
                                       off = i - NX - NW1 - NB1 - NW2; }
    float v;
    if (isf32) v = ((const float*)s)[off];
    else v = __uint_as_float((unsigned int)((const unsigned short*)s)[off] << 16);
    d[off] = (bf16)v;
  }
}

// ---------------------------------------------------------------------------
// NT GEMM: C[M,N] = A[M,K] * B[N,K]^T + bias[N]   (all bf16 in, fp32 acc)
// 128x128 block tile, BK=32, 256 threads (4 waves, 2x2 of 64x64 wave tiles)
// MODE 0: QKV epilogue -> scatter q [BH,S,Dh], k [BH,S,Dh], v^T [BH,Dh,S]
// MODE 1: plain epilogue -> out[M, 2048], dtype per *flagp (fp32/bf16)
// ---------------------------------------------------------------------------
template <int MODE>
__global__ __launch_bounds__(256, 2) void gemm_nt(
    const bf16* __restrict__ A, const bf16* __restrict__ B,
    const bf16* __restrict__ bias, int K,
    void* __restrict__ out0v, bf16* __restrict__ out1, bf16* __restrict__ out2,
    const int* __restrict__ flagp)
{
  __shared__ bf16 sA[128 * 32];
  __shared__ bf16 sB[128 * 32];
  const int t = threadIdx.x;
  const int lane = t & 63, w = t >> 6;
  const int wm = w >> 1, wn = w & 1;
  const int lr = lane & 15, lq = lane >> 4;
  const int m0 = blockIdx.y * 128, n0 = blockIdx.x * 128;

  f32x4 acc[4][4];
#pragma unroll
  for (int i = 0; i < 4; ++i)
#pragma unroll
    for (int j = 0; j < 4; ++j) acc[i][j] = (f32x4){0.f, 0.f, 0.f, 0.f};

  const bf16* Abase = A + (size_t)m0 * K;
  const bf16* Bbase = B + (size_t)n0 * K;
  const int nK = K >> 5;
  for (int kk = 0; kk < nK; ++kk) {
    const int k0 = kk << 5;
    bf16x8 ra[2], rb[2];
#pragma unroll
    for (int i = 0; i < 2; ++i) {
      const int c = i * 256 + t;
      ra[i] = *(const bf16x8*)(Abase + (size_t)(c >> 2) * K + k0 + (c & 3) * 8);
      rb[i] = *(const bf16x8*)(Bbase + (size_t)(c >> 2) * K + k0 + (c & 3) * 8);
    }
    __syncthreads();
#pragma unroll
    for (int i = 0; i < 2; ++i) {
      const int c = i * 256 + t;
      *(bf16x8*)(sA + (c >> 2) * 32 + (c & 3) * 8) = ra[i];
      *(bf16x8*)(sB + (c >> 2) * 32 + (c & 3) * 8) = rb[i];
    }
    __syncthreads();

    bf16x8 af[4], bfr[4];
#pragma unroll
    for (int mi = 0; mi < 4; ++mi)
      af[mi] = *(const bf16x8*)(sA + (wm * 64 + mi * 16 + lr) * 32 + lq * 8);
#pragma unroll
    for (int ni = 0; ni < 4; ++ni)
      bfr[ni] = *(const bf16x8*)(sB + (wn * 64 + ni * 16 + lr) * 32 + lq * 8);
#pragma unroll
    for (int mi = 0; mi < 4; ++mi)
#pragma unroll
      for (int ni = 0; ni < 4; ++ni)
        acc[mi][ni] = mfma_16x16x32(af[mi], bfr[ni], acc[mi][ni]);
  }

  // epilogue: C/D layout col = lane&15, row = (lane>>4)*4 + reg
  if (MODE == 0) {
    const int which = n0 >> 11;          // 0=q 1=k 2=v (N tile 128-aligned)
    const int h = (n0 >> 7) & 15;
    const int bb = m0 >> 11;
    const int s0 = m0 & 2047;
    bf16* dst = (which == 0) ? (bf16*)out0v : (which == 1) ? out1 : out2;
#pragma unroll
    for (int ni = 0; ni < 4; ++ni) {
      const int col = wn * 64 + ni * 16 + lr;   // d in [0,128)
      const float bv = (float)bias[n0 + col];
#pragma unroll
      for (int mi = 0; mi < 4; ++mi)
#pragma unroll
        for (int reg = 0; reg < 4; ++reg) {
          const int row = wm * 64 + mi * 16 + lq * 4 + reg;
          const int s = s0 + row;
          const float v = acc[mi][ni][reg] + bv;
          if (which == 2)  // V transposed: [BH, Dh, S]
            dst[((size_t)(bb * NHEAD + h) * DHEAD + col) * SEQ + s] = (bf16)v;
          else             // Q/K: [BH, S, Dh]
            dst[((size_t)(bb * NHEAD + h) * SEQ + s) * DHEAD + col] = (bf16)v;
        }
    }
  } else {
    const int isf32 = *flagp;
#pragma unroll
    for (int ni = 0; ni < 4; ++ni) {
      const int col = wn * 64 + ni * 16 + lr;
      const float bv = (float)bias[n0 + col];
#pragma unroll
      for (int mi = 0; mi < 4; ++mi)
#pragma unroll
        for (int reg = 0; reg < 4; ++reg) {
          const int row = wm * 64 + mi * 16 + lq * 4 + reg;
          const float v = acc[mi][ni][reg] + bv;
          const size_t idx = (size_t)(m0 + row) * EMBED + n0 + col;
          if (isf32) ((float*)out0v)[idx] = v;
          else       ((bf16*)out0v)[idx] = (bf16)v;
        }
    }
  }
}

// ---------------------------------------------------------------------------
// Causal flash attention. One block per (bh, q-tile of 64 rows).
// 4 waves; wave w owns q rows [qt*64 + w*16, +16). K/V tiles of 64 rows.
// No infinities anywhere: finite sentinel NEG_BIG; exp underflows to 0.
// ---------------------------------------------------------------------------
__global__ __launch_bounds__(256, 2) void attn_fwd(
    const bf16* __restrict__ qb, const bf16* __restrict__ kb,
    const bf16* __restrict__ vt, bf16* __restrict__ aout)
{
  __shared__ bf16 sK[64 * 136];   // [kcol][d], +8 pad
  __shared__ bf16 sV[128 * 72];   // [d][k], +8 pad (V already transposed)
  __shared__ bf16 sP[64 * 72];    // [q][k], +8 pad
  const int t = threadIdx.x;
  const int lane = t & 63, w = t >> 6;
  const int lr = lane & 15, lq = lane >> 4;
  const int qt = blockIdx.x & 31;
  const int bh = blockIdx.x >> 5;
  const int bb = bh >> 4, h = bh & 15;
  const float scale = 0.08838834764831845f;  // 1/sqrt(128)

  // Q fragments: A[m=lane&15][k=lq*8+j], 4 k-steps of 32 over Dh
  bf16x8 aq[4];
  {
    const bf16* qp =
        qb + ((size_t)bh * SEQ + qt * 64 + w * 16 + lr) * DHEAD + lq * 8;
#pragma unroll
    for (int ks = 0; ks < 4; ++ks) aq[ks] = *(const bf16x8*)(qp + ks * 32);
  }

  f32x4 oacc[8];
#pragma unroll
  for (int i = 0; i < 8; ++i) oacc[i] = (f32x4){0.f, 0.f, 0.f, 0.f};
  float m_i[4] = {NEG_BIG, NEG_BIG, NEG_BIG, NEG_BIG};
  float l_i[4] = {0.f, 0.f, 0.f, 0.f};

  for (int kt = 0; kt <= qt; ++kt) {
    __syncthreads();  // prior iter's LDS reads done in all waves
    // stage K tile 64x128 -> sK[kr][d]
#pragma unroll
    for (int i = 0; i < 4; ++i) {
      const int c = i * 256 + t;
      const int kr = c >> 4, dc = c & 15;
      *(bf16x8*)(sK + kr * 136 + dc * 8) = *(const bf16x8*)(
          kb + ((size_t)bh * SEQ + kt * 64 + kr) * DHEAD + dc * 8);
    }
    // stage V^T tile 128x64 -> sV[d][k]
#pragma unroll
    for (int i = 0; i < 4; ++i) {
      const int c = i * 256 + t;
      const int dr = c >> 3, kc = c & 7;
      *(bf16x8*)(sV + dr * 72 + kc * 8) = *(const bf16x8*)(
          vt + ((size_t)bh * DHEAD + dr) * SEQ + kt * 64 + kc * 8);
    }
    __syncthreads();

    // S = Q K^T (16x64 stripe per wave)
    f32x4 sacc[4];
#pragma unroll
    for (int ni = 0; ni < 4; ++ni) sacc[ni] = (f32x4){0.f, 0.f, 0.f, 0.f};
#pragma unroll
    for (int ks = 0; ks < 4; ++ks)
#pragma unroll
      for (int ni = 0; ni < 4; ++ni) {
        bf16x8 bk =
            *(const bf16x8*)(sK + (ni * 16 + lr) * 136 + ks * 32 + lq * 8);
        sacc[ni] = mfma_16x16x32(aq[ks], bk, sacc[ni]);
      }

    // scale + causal mask + online softmax (row q = lq*4+reg, col k = ni*16+lr)
    float p[4][4];
#pragma unroll
    for (int ni = 0; ni < 4; ++ni)
#pragma unroll
      for (int reg = 0; reg < 4; ++reg) {
        float sv = sacc[ni][reg] * scale;
        if (kt == qt) {
          const int kg = kt * 64 + ni * 16 + lr;
          const int qg = qt * 64 + w * 16 + lq * 4 + reg;
          if (kg > qg) sv = NEG_BIG;
        }
        p[ni][reg] = sv;
      }
#pragma unroll
    for (int reg = 0; reg < 4; ++reg) {
      float mx = fmaxf(fmaxf(p[0][reg], p[1][reg]), fmaxf(p[2][reg], p[3][reg]));
#pragma unroll
      for (int off = 1; off < 16; off <<= 1)
        mx = fmaxf(mx, __shfl_xor(mx, off, 64));
      const float mnew = fmaxf(m_i[reg], mx);
      const float alpha = __expf(m_i[reg] - mnew);  // underflows to 0 first tile
      float ls = 0.f;
#pragma unroll
      for (int ni = 0; ni < 4; ++ni) {
        p[ni][reg] = __expf(p[ni][reg] - mnew);
        ls += p[ni][reg];
      }
#pragma unroll
      for (int off = 1; off < 16; off <<= 1) ls += __shfl_xor(ls, off, 64);
      l_i[reg] = l_i[reg] * alpha + ls;
      m_i[reg] = mnew;
#pragma unroll
      for (int dt = 0; dt < 8; ++dt) oacc[dt][reg] *= alpha;
    }

    // P (C-layout regs) -> LDS [q][k] for A-operand reads
#pragma unroll
    for (int ni = 0; ni < 4; ++ni)
#pragma unroll
      for (int reg = 0; reg < 4; ++reg)
        sP[(w * 16 + lq * 4 + reg) * 72 + ni * 16 + lr] = (bf16)p[ni][reg];
    __syncthreads();

    // O += P V  (A = P[q][k], B = V^T[d][k])
#pragma unroll
    for (int ks2 = 0; ks2 < 2; ++ks2) {
      bf16x8 ap = *(const bf16x8*)(sP + (w * 16 + lr) * 72 + ks2 * 32 + lq * 8);
#pragma unroll
      for (int dt = 0; dt < 8; ++dt) {
        bf16x8 bv =
            *(const bf16x8*)(sV + (dt * 16 + lr) * 72 + ks2 * 32 + lq * 8);
        oacc[dt] = mfma_16x16x32(ap, bv, oacc[dt]);
      }
    }
  }

  // epilogue: O / l -> aout [B, S, E] (E index = h*128 + d), bf16 internal
  float inv[4];
#pragma unroll
  for (int reg = 0; reg < 4; ++reg) inv[reg] = 1.0f / l_i[reg];
#pragma unroll
  for (int dt = 0; dt < 8; ++dt)
#pragma unroll
    for (int reg = 0; reg < 4; ++reg) {
      const int qg = qt * 64 + w * 16 + lq * 4 + reg;
      aout[((size_t)bb * SEQ + qg) * EMBED + h * 128 + dt * 16 + lr] =
          (bf16)(oacc[dt][reg] * inv[reg]);
    }
}

extern "C" void kernel_launch(void* const* d_in, const int* in_sizes, int n_in,
                              void* d_out, int out_size, void* d_ws, size_t ws_size,
                              hipStream_t stream) {
  const void* x    = d_in[0];
  const void* Wqkv = d_in[1];
  const void* bqkv = d_in[2];
  const void* Wout = d_in[3];
  const void* bout = d_in[4];
  // d_in[5] = causal mask; structure (strict upper triangle) is baked in.

  int* flagp = (int*)d_ws;
  bf16* base = (bf16*)((char*)d_ws + 256);
  bf16* xb   = base;
  bf16* w1b  = xb + NX;
  bf16* b1b  = w1b + NW1;
  bf16* w2b  = b1b + NB1;
  bf16* b2b  = w2b + NW2;
  bf16* qb   = b2b + NB2;
  bf16* kb   = qb + NX;
  bf16* vt   = kb + NX;
  bf16* aout = vt + NX;
  // total: ~112 MiB of ws

  dim3 blk(256);
  convert_inputs<<<dim3(4096), blk, 0, stream>>>(
      x, Wqkv, bqkv, Wout, bout, xb, w1b, b1b, w2b, b2b, flagp);
  // QKV projection: M=4096, N=6144, K=2048
  gemm_nt<0><<<dim3(48, 32), blk, 0, stream>>>(xb, w1b, b1b, EMBED,
                                               (void*)qb, kb, vt, flagp);
  // attention: 32 bh * 32 q-tiles
  attn_fwd<<<dim3(1024), blk, 0, stream>>>(qb, kb, vt, aout);
  // out projection: M=4096, N=2048, K=2048
  gemm_nt<1><<<dim3(16, 32), blk, 0, stream>>>(aout, w2b, b2b, EMBED,
                                               d_out, nullptr, nullptr, flagp);
}

// Round 4
// 503.095 us; speedup vs baseline: 1.0847x; 1.0847x over previous
//
#include <hip/hip_runtime.h>
#include <hip/hip_bf16.h>
#include <math.h>

#define SEQ   2048
#define EMBED 2048
#define NHEAD 16
#define DHEAD 128
#define BATCH 2

#define NX   ((size_t)BATCH * SEQ * EMBED)   // 8388608
#define NW1  ((size_t)3 * EMBED * EMBED)     // 12582912
#define NB1  ((size_t)3 * EMBED)             // 6144
#define NW2  ((size_t)EMBED * EMBED)         // 4194304
#define NB2  ((size_t)EMBED)                 // 2048

typedef __bf16 bf16;
typedef __attribute__((__ext_vector_type__(8))) __bf16 bf16x8;
typedef __attribute__((__ext_vector_type__(4))) float f32x4;
typedef __attribute__((__ext_vector_type__(4))) unsigned int u32x4;

#define NEG_BIG (-1.0e30f)

__device__ __forceinline__ f32x4 mfma_16x16x32(bf16x8 a, bf16x8 b, f32x4 c) {
  return __builtin_amdgcn_mfma_f32_16x16x32_bf16(a, b, c, 0, 0, 0);
}

// async global->LDS, 16B per lane; dst is wave-uniform base, lane i lands at
// dst + i*16B (m97-verified pattern)
__device__ __forceinline__ void llds16(bf16* dst, const bf16* src) {
  __builtin_amdgcn_global_load_lds(
      (const __attribute__((address_space(1))) void*)src,
      (__attribute__((address_space(3))) void*)dst, 16, 0, 0);
}

// ---------------------------------------------------------------------------
// Input normalization: detect fp32 vs bf16 storage, convert to bf16 ws.
// Vectorized: 8 elems/thread/iter (32B fp32 in -> 16B bf16 out).
// ---------------------------------------------------------------------------
__global__ void convert_inputs(const void* __restrict__ xin,
                               const void* __restrict__ w1in,
                               const void* __restrict__ b1in,
                               const void* __restrict__ w2in,
                               const void* __restrict__ b2in,
                               bf16* __restrict__ xb, bf16* __restrict__ w1b,
                               bf16* __restrict__ b1b, bf16* __restrict__ w2b,
                               bf16* __restrict__ b2b, int* __restrict__ flagp)
{
  __shared__ int sflag;
  if (threadIdx.x == 0) sflag = 0;
  __syncthreads();
  const unsigned short* xh = (const unsigned short*)xin;
  int huge = 0;
  for (int i = threadIdx.x; i < 2048; i += 256) {
    float f = __uint_as_float((unsigned int)xh[i] << 16);
    if (!(fabsf(f) <= 1e4f)) huge = 1;  // catches NaN/Inf too
  }
  if (huge) sflag = 1;
  __syncthreads();
  const int isf32 = sflag;
  if (blockIdx.x == 0 && threadIdx.x == 0) *flagp = isf32;

  const void* srcs[5] = {xin, w1in, b1in, w2in, b2in};
  bf16* dsts[5] = {xb, w1b, b1b, w2b, b2b};
  const size_t lens[5] = {NX, NW1, NB1, NW2, NB2};
  const size_t gid = (size_t)blockIdx.x * blockDim.x + threadIdx.x;
  const size_t gstride = (size_t)gridDim.x * blockDim.x;
  for (int sidx = 0; sidx < 5; ++sidx) {
    const size_t n8 = lens[sidx] >> 3;
    bf16* d = dsts[sidx];
    if (isf32) {
      const float* s = (const float*)srcs[sidx];
      for (size_t i = gid; i < n8; i += gstride) {
        const float* sp = s + i * 8;
        bf16x8 r;
#pragma unroll
        for (int j = 0; j < 8; ++j) r[j] = (bf16)sp[j];
        *(bf16x8*)(d + i * 8) = r;
      }
    } else {
      const u32x4* s = (const u32x4*)srcs[sidx];
      for (size_t i = gid; i < n8; i += gstride)
        *(u32x4*)(d + i * 8) = s[i];
    }
  }
}

// ---------------------------------------------------------------------------
// NT GEMM: C[M,N] = A[M,K] * B[N,K]^T + bias[N]  (bf16 in, fp32 acc)
// m97 structure: 128x128 tile, BK=32, global_load_lds width-16 staging.
// MODE 0: QKV epilogue -> q [BH,S,Dh], k [BH,S,Dh], v^T [BH,Dh,S]
// MODE 1: plain epilogue -> out[M, 2048], dtype per *flagp
// ---------------------------------------------------------------------------
template <int MODE>
__global__ __launch_bounds__(256, 2) void gemm_nt(
    const bf16* __restrict__ A, const bf16* __restrict__ B,
    const bf16* __restrict__ bias, int K,
    void* __restrict__ out0v, bf16* __restrict__ out1, bf16* __restrict__ out2,
    const int* __restrict__ flagp)
{
  __shared__ bf16 sA[128 * 32];
  __shared__ bf16 sB[128 * 32];
  const int t = threadIdx.x;
  const int lane = t & 63, w = t >> 6;
  const int wm = w >> 1, wn = w & 1;
  const int lr = lane & 15, lq = lane >> 4;
  const int m0 = blockIdx.y * 128, n0 = blockIdx.x * 128;

  f32x4 acc[4][4];
#pragma unroll
  for (int i = 0; i < 4; ++i)
#pragma unroll
    for (int j = 0; j < 4; ++j) acc[i][j] = (f32x4){0.f, 0.f, 0.f, 0.f};

  const bf16* Abase = A + (size_t)m0 * K;
  const bf16* Bbase = B + (size_t)n0 * K;
  const int nK = K >> 5;
  for (int kk = 0; kk < nK; ++kk) {
    const int k0 = kk << 5;
    __syncthreads();  // prior iteration's LDS reads complete
#pragma unroll
    for (int i = 0; i < 2; ++i) {
      const int c = i * 256 + t;
      const int ldsbase = (i * 256 + (t & ~63)) << 3;  // wave-uniform elems
      llds16(sA + ldsbase, Abase + (size_t)(c >> 2) * K + k0 + (c & 3) * 8);
      llds16(sB + ldsbase, Bbase + (size_t)(c >> 2) * K + k0 + (c & 3) * 8);
    }
    __syncthreads();  // vmcnt drain: staging visible

    bf16x8 af[4], bfr[4];
#pragma unroll
    for (int mi = 0; mi < 4; ++mi)
      af[mi] = *(const bf16x8*)(sA + (wm * 64 + mi * 16 + lr) * 32 + lq * 8);
#pragma unroll
    for (int ni = 0; ni < 4; ++ni)
      bfr[ni] = *(const bf16x8*)(sB + (wn * 64 + ni * 16 + lr) * 32 + lq * 8);
#pragma unroll
    for (int mi = 0; mi < 4; ++mi)
#pragma unroll
      for (int ni = 0; ni < 4; ++ni)
        acc[mi][ni] = mfma_16x16x32(af[mi], bfr[ni], acc[mi][ni]);
  }

  // epilogue: C/D layout col = lane&15, row = (lane>>4)*4 + reg
  if (MODE == 0) {
    const int which = n0 >> 11;
    const int h = (n0 >> 7) & 15;
    const int bb = m0 >> 11;
    const int s0 = m0 & 2047;
    bf16* dst = (which == 0) ? (bf16*)out0v : (which == 1) ? out1 : out2;
#pragma unroll
    for (int ni = 0; ni < 4; ++ni) {
      const int col = wn * 64 + ni * 16 + lr;
      const float bv = (float)bias[n0 + col];
#pragma unroll
      for (int mi = 0; mi < 4; ++mi)
#pragma unroll
        for (int reg = 0; reg < 4; ++reg) {
          const int row = wm * 64 + mi * 16 + lq * 4 + reg;
          const int s = s0 + row;
          const float v = acc[mi][ni][reg] + bv;
          if (which == 2)
            dst[((size_t)(bb * NHEAD + h) * DHEAD + col) * SEQ + s] = (bf16)v;
          else
            dst[((size_t)(bb * NHEAD + h) * SEQ + s) * DHEAD + col] = (bf16)v;
        }
    }
  } else {
    const int isf32 = *flagp;
#pragma unroll
    for (int ni = 0; ni < 4; ++ni) {
      const int col = wn * 64 + ni * 16 + lr;
      const float bv = (float)bias[n0 + col];
#pragma unroll
      for (int mi = 0; mi < 4; ++mi)
#pragma unroll
        for (int reg = 0; reg < 4; ++reg) {
          const int row = wm * 64 + mi * 16 + lq * 4 + reg;
          const float v = acc[mi][ni][reg] + bv;
          const size_t idx = (size_t)(m0 + row) * EMBED + n0 + col;
          if (isf32) ((float*)out0v)[idx] = v;
          else       ((bf16*)out0v)[idx] = (bf16)v;
        }
    }
  }
}

// ---------------------------------------------------------------------------
// Causal flash attention, pair-balanced: block (bh, p) handles q-tiles
// {p, 31-p} (64 rows each) over the shared K range kt=0..31-p.
// Work per block = 33 tile-computations, constant. K/V staged via register
// prefetch issued before the compute phase (latency hidden under MFMA).
// sP is wave-private -> wave-level lgkmcnt wait, no block barrier.
// ---------------------------------------------------------------------------
__device__ __forceinline__ void qk_softmax_tile(
    const bf16* __restrict__ sK, bf16* __restrict__ sP, const bf16x8* aq,
    float* m_i, float* l_i, f32x4* oacc, int kt, int qt,
    int w, int lr, int lq, int sPofs)
{
  const float scale = 0.08838834764831845f;  // 1/sqrt(128)
  f32x4 sacc[4];
#pragma unroll
  for (int ni = 0; ni < 4; ++ni) sacc[ni] = (f32x4){0.f, 0.f, 0.f, 0.f};
#pragma unroll
  for (int ks = 0; ks < 4; ++ks)
#pragma unroll
    for (int ni = 0; ni < 4; ++ni) {
      bf16x8 bk = *(const bf16x8*)(sK + (ni * 16 + lr) * 136 + ks * 32 + lq * 8);
      sacc[ni] = mfma_16x16x32(aq[ks], bk, sacc[ni]);
    }
  float pp[4][4];
#pragma unroll
  for (int ni = 0; ni < 4; ++ni)
#pragma unroll
    for (int reg = 0; reg < 4; ++reg) {
      float sv = sacc[ni][reg] * scale;
      if (kt == qt) {
        const int kg = kt * 64 + ni * 16 + lr;
        const int qg = qt * 64 + w * 16 + lq * 4 + reg;
        if (kg > qg) sv = NEG_BIG;
      }
      pp[ni][reg] = sv;
    }
#pragma unroll
  for (int reg = 0; reg < 4; ++reg) {
    float mx = fmaxf(fmaxf(pp[0][reg], pp[1][reg]), fmaxf(pp[2][reg], pp[3][reg]));
#pragma unroll
    for (int off = 1; off < 16; off <<= 1)
      mx = fmaxf(mx, __shfl_xor(mx, off, 64));
    const float mnew = fmaxf(m_i[reg], mx);
    const float alpha = __expf(m_i[reg] - mnew);
    float ls = 0.f;
#pragma unroll
    for (int ni = 0; ni < 4; ++ni) {
      pp[ni][reg] = __expf(pp[ni][reg] - mnew);
      ls += pp[ni][reg];
    }
#pragma unroll
    for (int off = 1; off < 16; off <<= 1) ls += __shfl_xor(ls, off, 64);
    l_i[reg] = l_i[reg] * alpha + ls;
    m_i[reg] = mnew;
#pragma unroll
    for (int dt = 0; dt < 8; ++dt) oacc[dt][reg] *= alpha;
  }
#pragma unroll
  for (int ni = 0; ni < 4; ++ni)
#pragma unroll
    for (int reg = 0; reg < 4; ++reg)
      sP[(sPofs + w * 16 + lq * 4 + reg) * 72 + ni * 16 + lr] =
          (bf16)pp[ni][reg];
}

__device__ __forceinline__ void pv_tile(const bf16* __restrict__ sP,
                                        const bf16* __restrict__ sV,
                                        f32x4* oacc, int w, int lr, int lq,
                                        int sPofs)
{
#pragma unroll
  for (int ks2 = 0; ks2 < 2; ++ks2) {
    bf16x8 ap =
        *(const bf16x8*)(sP + (sPofs + w * 16 + lr) * 72 + ks2 * 32 + lq * 8);
#pragma unroll
    for (int dt = 0; dt < 8; ++dt) {
      bf16x8 bv =
          *(const bf16x8*)(sV + (dt * 16 + lr) * 72 + ks2 * 32 + lq * 8);
      oacc[dt] = mfma_16x16x32(ap, bv, oacc[dt]);
    }
  }
}

__global__ __launch_bounds__(256, 2) void attn_fwd(
    const bf16* __restrict__ qb, const bf16* __restrict__ kb,
    const bf16* __restrict__ vt, bf16* __restrict__ aout)
{
  __shared__ bf16 sK[64 * 136];    // [k][d], +8 pad
  __shared__ bf16 sV[128 * 72];    // [d][k], +8 pad
  __shared__ bf16 sP[128 * 72];    // [q][k]: rows 0-63 lo tile, 64-127 hi
  const int t = threadIdx.x;
  const int lane = t & 63, w = t >> 6;
  const int lr = lane & 15, lq = lane >> 4;
  const int p  = blockIdx.x & 15;
  const int bh = blockIdx.x >> 4;
  const int bb = bh >> 4, h = bh & 15;
  const int qlo = p, qhi = 31 - p;

  // Q fragments for both tiles: A[m=lr][k=lq*8+j]
  bf16x8 aqL[4], aqH[4];
  {
    const bf16* qpL =
        qb + ((size_t)bh * SEQ + qlo * 64 + w * 16 + lr) * DHEAD + lq * 8;
    const bf16* qpH =
        qb + ((size_t)bh * SEQ + qhi * 64 + w * 16 + lr) * DHEAD + lq * 8;
#pragma unroll
    for (int ks = 0; ks < 4; ++ks) {
      aqL[ks] = *(const bf16x8*)(qpL + ks * 32);
      aqH[ks] = *(const bf16x8*)(qpH + ks * 32);
    }
  }

  f32x4 oL[8], oH[8];
#pragma unroll
  for (int i = 0; i < 8; ++i) {
    oL[i] = (f32x4){0.f, 0.f, 0.f, 0.f};
    oH[i] = (f32x4){0.f, 0.f, 0.f, 0.f};
  }
  float mL[4] = {NEG_BIG, NEG_BIG, NEG_BIG, NEG_BIG};
  float mH[4] = {NEG_BIG, NEG_BIG, NEG_BIG, NEG_BIG};
  float lL[4] = {0.f, 0.f, 0.f, 0.f};
  float lH[4] = {0.f, 0.f, 0.f, 0.f};

  // register prefetch buffers for K/V tiles
  bf16x8 rk[4], rv[4];
  const int kr_ = t >> 4, kd_ = t & 15;   // strides for K staging (c = i*256+t)
  const int vr_ = t >> 3, vk_ = t & 7;
#define FETCH(ktv)                                                          \
  {                                                                         \
    const int _kt = (ktv);                                                  \
    _Pragma("unroll") for (int i = 0; i < 4; ++i) {                         \
      rk[i] = *(const bf16x8*)(kb + ((size_t)bh * SEQ + _kt * 64 +          \
                                     (i * 16 + kr_)) * DHEAD + kd_ * 8);    \
      rv[i] = *(const bf16x8*)(vt + ((size_t)bh * DHEAD + (i * 32 + vr_)) * \
                                     SEQ + _kt * 64 + vk_ * 8);             \
    }                                                                       \
  }
#define COMMIT()                                                            \
  {                                                                         \
    _Pragma("unroll") for (int i = 0; i < 4; ++i) {                         \
      *(bf16x8*)(sK + (i * 16 + kr_) * 136 + kd_ * 8) = rk[i];              \
      *(bf16x8*)(sV + (i * 32 + vr_) * 72 + vk_ * 8) = rv[i];               \
    }                                                                       \
  }

  FETCH(0);
  COMMIT();
  __syncthreads();

  for (int kt = 0; kt <= qhi; ++kt) {
    if (kt < qhi) FETCH(kt + 1);           // latency spans the compute phase
    const bool doLo = (kt <= qlo);         // block-uniform

    qk_softmax_tile(sK, sP, aqH, mH, lH, oH, kt, qhi, w, lr, lq, 64);
    if (doLo) qk_softmax_tile(sK, sP, aqL, mL, lL, oL, kt, qlo, w, lr, lq, 0);
    // sP is wave-private (each wave reads only its own 16 rows per tile):
    // wave-level LDS drain is sufficient, no block barrier.
    asm volatile("s_waitcnt lgkmcnt(0)" ::: "memory");
    pv_tile(sP, sV, oH, w, lr, lq, 64);
    if (doLo) pv_tile(sP, sV, oL, w, lr, lq, 0);

    __syncthreads();                       // all sK/sV/sP reads complete
    if (kt < qhi) {
      COMMIT();
      __syncthreads();                     // staging visible
    }
  }

  // epilogue: O / l -> aout [B, S, E]
#pragma unroll
  for (int side = 0; side < 2; ++side) {
    const f32x4* oacc = side ? oH : oL;
    const float* l_i = side ? lH : lL;
    const int qt = side ? qhi : qlo;
    float inv[4];
#pragma unroll
    for (int reg = 0; reg < 4; ++reg) inv[reg] = 1.0f / l_i[reg];
#pragma unroll
    for (int dt = 0; dt < 8; ++dt)
#pragma unroll
      for (int reg = 0; reg < 4; ++reg) {
        const int qg = qt * 64 + w * 16 + lq * 4 + reg;
        aout[((size_t)bb * SEQ + qg) * EMBED + h * 128 + dt * 16 + lr] =
            (bf16)(oacc[dt][reg] * inv[reg]);
      }
  }
#undef FETCH
#undef COMMIT
}

extern "C" void kernel_launch(void* const* d_in, const int* in_sizes, int n_in,
                              void* d_out, int out_size, void* d_ws, size_t ws_size,
                              hipStream_t stream) {
  const void* x    = d_in[0];
  const void* Wqkv = d_in[1];
  const void* bqkv = d_in[2];
  const void* Wout = d_in[3];
  const void* bout = d_in[4];

  int* flagp = (int*)d_ws;
  bf16* base = (bf16*)((char*)d_ws + 256);
  bf16* xb   = base;
  bf16* w1b  = xb + NX;
  bf16* b1b  = w1b + NW1;
  bf16* w2b  = b1b + NB1;
  bf16* b2b  = w2b + NW2;
  bf16* qb   = b2b + NB2;
  bf16* kb   = qb + NX;
  bf16* vt   = kb + NX;
  bf16* aout = vt + NX;

  dim3 blk(256);
  convert_inputs<<<dim3(1024), blk, 0, stream>>>(
      x, Wqkv, bqkv, Wout, bout, xb, w1b, b1b, w2b, b2b, flagp);
  // QKV projection: M=4096, N=6144, K=2048
  gemm_nt<0><<<dim3(48, 32), blk, 0, stream>>>(xb, w1b, b1b, EMBED,
                                               (void*)qb, kb, vt, flagp);
  // attention: 32 bh * 16 balanced pairs
  attn_fwd<<<dim3(512), blk, 0, stream>>>(qb, kb, vt, aout);
  // out projection: M=4096, N=2048, K=2048
  gemm_nt<1><<<dim3(16, 32), blk, 0, stream>>>(aout, w2b, b2b, EMBED,
                                               d_out, nullptr, nullptr, flagp);
}

// Round 5
// 479.768 us; speedup vs baseline: 1.1374x; 1.0486x over previous
//
#include <hip/hip_runtime.h>
#include <hip/hip_bf16.h>
#include <math.h>

#define SEQ   2048
#define EMBED 2048
#define NHEAD 16
#define DHEAD 128
#define BATCH 2

#define NX   ((size_t)BATCH * SEQ * EMBED)   // 8388608
#define NW1  ((size_t)3 * EMBED * EMBED)     // 12582912
#define NB1  ((size_t)3 * EMBED)             // 6144
#define NW2  ((size_t)EMBED * EMBED)         // 4194304
#define NB2  ((size_t)EMBED)                 // 2048

typedef __bf16 bf16;
typedef __attribute__((__ext_vector_type__(8))) __bf16 bf16x8;
typedef __attribute__((__ext_vector_type__(4))) __bf16 bf16x4;
typedef __attribute__((__ext_vector_type__(4))) float f32x4;
typedef __attribute__((__ext_vector_type__(4))) unsigned int u32x4;

#define NEG_BIG (-1.0e30f)

__device__ __forceinline__ f32x4 mfma_16x16x32(bf16x8 a, bf16x8 b, f32x4 c) {
  return __builtin_amdgcn_mfma_f32_16x16x32_bf16(a, b, c, 0, 0, 0);
}

// async global->LDS, 16B per lane; dst is wave-uniform base, lane i lands at
// dst + i*16B (m97-verified pattern)
__device__ __forceinline__ void llds16(bf16* dst, const bf16* src) {
  __builtin_amdgcn_global_load_lds(
      (const __attribute__((address_space(1))) void*)src,
      (__attribute__((address_space(3))) void*)dst, 16, 0, 0);
}

// ---------------------------------------------------------------------------
// Input normalization: detect fp32 vs bf16 storage, convert to bf16 ws.
// ---------------------------------------------------------------------------
__global__ void convert_inputs(const void* __restrict__ xin,
                               const void* __restrict__ w1in,
                               const void* __restrict__ b1in,
                               const void* __restrict__ w2in,
                               const void* __restrict__ b2in,
                               bf16* __restrict__ xb, bf16* __restrict__ w1b,
                               bf16* __restrict__ b1b, bf16* __restrict__ w2b,
                               bf16* __restrict__ b2b, int* __restrict__ flagp)
{
  __shared__ int sflag;
  if (threadIdx.x == 0) sflag = 0;
  __syncthreads();
  const unsigned short* xh = (const unsigned short*)xin;
  int huge = 0;
  for (int i = threadIdx.x; i < 2048; i += 256) {
    float f = __uint_as_float((unsigned int)xh[i] << 16);
    if (!(fabsf(f) <= 1e4f)) huge = 1;  // catches NaN/Inf too
  }
  if (huge) sflag = 1;
  __syncthreads();
  const int isf32 = sflag;
  if (blockIdx.x == 0 && threadIdx.x == 0) *flagp = isf32;

  const void* srcs[5] = {xin, w1in, b1in, w2in, b2in};
  bf16* dsts[5] = {xb, w1b, b1b, w2b, b2b};
  const size_t lens[5] = {NX, NW1, NB1, NW2, NB2};
  const size_t gid = (size_t)blockIdx.x * blockDim.x + threadIdx.x;
  const size_t gstride = (size_t)gridDim.x * blockDim.x;
  for (int sidx = 0; sidx < 5; ++sidx) {
    const size_t n8 = lens[sidx] >> 3;
    bf16* d = dsts[sidx];
    if (isf32) {
      const float* s = (const float*)srcs[sidx];
      for (size_t i = gid; i < n8; i += gstride) {
        const float* sp = s + i * 8;
        bf16x8 r;
#pragma unroll
        for (int j = 0; j < 8; ++j) r[j] = (bf16)sp[j];
        *(bf16x8*)(d + i * 8) = r;
      }
    } else {
      const u32x4* s = (const u32x4*)srcs[sidx];
      for (size_t i = gid; i < n8; i += gstride)
        *(u32x4*)(d + i * 8) = s[i];
    }
  }
}

// ---------------------------------------------------------------------------
// NT GEMM: C[M,N] = A[M,K] * B[N,K]^T + bias[N]  (bf16 in, fp32 acc)
// m97 structure: 128x128 tile, BK=32, global_load_lds width-16 staging.
// launch_bounds(256,4): 4 blocks/CU resident (VGPR ~120 unified, cap 128).
// MODE 0: QKV epilogue -> q [BH,S,Dh], k [BH,S,Dh], v^T [BH,Dh,S]
// MODE 1: plain epilogue -> out[M, 2048], dtype per *flagp
// ---------------------------------------------------------------------------
template <int MODE>
__global__ __launch_bounds__(256, 4) void gemm_nt(
    const bf16* __restrict__ A, const bf16* __restrict__ B,
    const bf16* __restrict__ bias, int K,
    void* __restrict__ out0v, bf16* __restrict__ out1, bf16* __restrict__ out2,
    const int* __restrict__ flagp)
{
  __shared__ bf16 sA[128 * 32];
  __shared__ bf16 sB[128 * 32];
  const int t = threadIdx.x;
  const int lane = t & 63, w = t >> 6;
  const int wm = w >> 1, wn = w & 1;
  const int lr = lane & 15, lq = lane >> 4;
  const int m0 = blockIdx.y * 128, n0 = blockIdx.x * 128;

  f32x4 acc[4][4];
#pragma unroll
  for (int i = 0; i < 4; ++i)
#pragma unroll
    for (int j = 0; j < 4; ++j) acc[i][j] = (f32x4){0.f, 0.f, 0.f, 0.f};

  const bf16* Abase = A + (size_t)m0 * K;
  const bf16* Bbase = B + (size_t)n0 * K;
  const int nK = K >> 5;
  for (int kk = 0; kk < nK; ++kk) {
    const int k0 = kk << 5;
    __syncthreads();  // prior iteration's LDS reads complete
#pragma unroll
    for (int i = 0; i < 2; ++i) {
      const int c = i * 256 + t;
      const int ldsbase = (i * 256 + (t & ~63)) << 3;  // wave-uniform elems
      llds16(sA + ldsbase, Abase + (size_t)(c >> 2) * K + k0 + (c & 3) * 8);
      llds16(sB + ldsbase, Bbase + (size_t)(c >> 2) * K + k0 + (c & 3) * 8);
    }
    __syncthreads();  // vmcnt drain: staging visible

    bf16x8 af[4], bfr[4];
#pragma unroll
    for (int mi = 0; mi < 4; ++mi)
      af[mi] = *(const bf16x8*)(sA + (wm * 64 + mi * 16 + lr) * 32 + lq * 8);
#pragma unroll
    for (int ni = 0; ni < 4; ++ni)
      bfr[ni] = *(const bf16x8*)(sB + (wn * 64 + ni * 16 + lr) * 32 + lq * 8);
#pragma unroll
    for (int mi = 0; mi < 4; ++mi)
#pragma unroll
      for (int ni = 0; ni < 4; ++ni)
        acc[mi][ni] = mfma_16x16x32(af[mi], bfr[ni], acc[mi][ni]);
  }

  // epilogue: C/D layout col = lane&15, row = (lane>>4)*4 + reg
  if (MODE == 0) {
    const int which = n0 >> 11;
    const int h = (n0 >> 7) & 15;
    const int bb = m0 >> 11;
    const int s0 = m0 & 2047;
    if (which == 2) {
      // V transposed: [BH, Dh, S]; 4 regs = 4 consecutive s -> 8B store
      bf16* dst = out2;
#pragma unroll
      for (int ni = 0; ni < 4; ++ni) {
        const int col = wn * 64 + ni * 16 + lr;
        const float bv = (float)bias[n0 + col];
        bf16* rowp = dst + ((size_t)(bb * NHEAD + h) * DHEAD + col) * SEQ + s0;
#pragma unroll
        for (int mi = 0; mi < 4; ++mi) {
          bf16x4 pk;
#pragma unroll
          for (int reg = 0; reg < 4; ++reg)
            pk[reg] = (bf16)(acc[mi][ni][reg] + bv);
          *(bf16x4*)(rowp + wm * 64 + mi * 16 + lq * 4) = pk;
        }
      }
    } else {
      bf16* dst = (which == 0) ? (bf16*)out0v : out1;
#pragma unroll
      for (int ni = 0; ni < 4; ++ni) {
        const int col = wn * 64 + ni * 16 + lr;
        const float bv = (float)bias[n0 + col];
#pragma unroll
        for (int mi = 0; mi < 4; ++mi)
#pragma unroll
          for (int reg = 0; reg < 4; ++reg) {
            const int row = wm * 64 + mi * 16 + lq * 4 + reg;
            const int s = s0 + row;
            dst[((size_t)(bb * NHEAD + h) * SEQ + s) * DHEAD + col] =
                (bf16)(acc[mi][ni][reg] + bv);
          }
      }
    }
  } else {
    const int isf32 = *flagp;
#pragma unroll
    for (int ni = 0; ni < 4; ++ni) {
      const int col = wn * 64 + ni * 16 + lr;
      const float bv = (float)bias[n0 + col];
#pragma unroll
      for (int mi = 0; mi < 4; ++mi)
#pragma unroll
        for (int reg = 0; reg < 4; ++reg) {
          const int row = wm * 64 + mi * 16 + lq * 4 + reg;
          const float v = acc[mi][ni][reg] + bv;
          const size_t idx = (size_t)(m0 + row) * EMBED + n0 + col;
          if (isf32) ((float*)out0v)[idx] = v;
          else       ((bf16*)out0v)[idx] = (bf16)v;
        }
    }
  }
}

// ---------------------------------------------------------------------------
// Causal flash attention, pair-balanced: block (bh, p) handles q-tiles
// {p, 31-p} (64 rows each) over the shared K range kt=0..31-p.
// ---------------------------------------------------------------------------
__device__ __forceinline__ void qk_softmax_tile(
    const bf16* __restrict__ sK, bf16* __restrict__ sP, const bf16x8* aq,
    float* m_i, float* l_i, f32x4* oacc, int kt, int qt,
    int w, int lr, int lq, int sPofs)
{
  const float scale = 0.08838834764831845f;  // 1/sqrt(128)
  f32x4 sacc[4];
#pragma unroll
  for (int ni = 0; ni < 4; ++ni) sacc[ni] = (f32x4){0.f, 0.f, 0.f, 0.f};
#pragma unroll
  for (int ks = 0; ks < 4; ++ks)
#pragma unroll
    for (int ni = 0; ni < 4; ++ni) {
      bf16x8 bk = *(const bf16x8*)(sK + (ni * 16 + lr) * 136 + ks * 32 + lq * 8);
      sacc[ni] = mfma_16x16x32(aq[ks], bk, sacc[ni]);
    }
  float pp[4][4];
#pragma unroll
  for (int ni = 0; ni < 4; ++ni)
#pragma unroll
    for (int reg = 0; reg < 4; ++reg) {
      float sv = sacc[ni][reg] * scale;
      if (kt == qt) {
        const int kg = kt * 64 + ni * 16 + lr;
        const int qg = qt * 64 + w * 16 + lq * 4 + reg;
        if (kg > qg) sv = NEG_BIG;
      }
      pp[ni][reg] = sv;
    }
#pragma unroll
  for (int reg = 0; reg < 4; ++reg) {
    float mx = fmaxf(fmaxf(pp[0][reg], pp[1][reg]), fmaxf(pp[2][reg], pp[3][reg]));
#pragma unroll
    for (int off = 1; off < 16; off <<= 1)
      mx = fmaxf(mx, __shfl_xor(mx, off, 64));
    const float mnew = fmaxf(m_i[reg], mx);
    const float alpha = __expf(m_i[reg] - mnew);
    float ls = 0.f;
#pragma unroll
    for (int ni = 0; ni < 4; ++ni) {
      pp[ni][reg] = __expf(pp[ni][reg] - mnew);
      ls += pp[ni][reg];
    }
#pragma unroll
    for (int off = 1; off < 16; off <<= 1) ls += __shfl_xor(ls, off, 64);
    l_i[reg] = l_i[reg] * alpha + ls;
    m_i[reg] = mnew;
#pragma unroll
    for (int dt = 0; dt < 8; ++dt) oacc[dt][reg] *= alpha;
  }
#pragma unroll
  for (int ni = 0; ni < 4; ++ni)
#pragma unroll
    for (int reg = 0; reg < 4; ++reg)
      sP[(sPofs + w * 16 + lq * 4 + reg) * 72 + ni * 16 + lr] =
          (bf16)pp[ni][reg];
}

__device__ __forceinline__ void pv_tile(const bf16* __restrict__ sP,
                                        const bf16* __restrict__ sV,
                                        f32x4* oacc, int w, int lr, int lq,
                                        int sPofs)
{
#pragma unroll
  for (int ks2 = 0; ks2 < 2; ++ks2) {
    bf16x8 ap =
        *(const bf16x8*)(sP + (sPofs + w * 16 + lr) * 72 + ks2 * 32 + lq * 8);
#pragma unroll
    for (int dt = 0; dt < 8; ++dt) {
      bf16x8 bv =
          *(const bf16x8*)(sV + (dt * 16 + lr) * 72 + ks2 * 32 + lq * 8);
      oacc[dt] = mfma_16x16x32(ap, bv, oacc[dt]);
    }
  }
}

__global__ __launch_bounds__(256, 2) void attn_fwd(
    const bf16* __restrict__ qb, const bf16* __restrict__ kb,
    const bf16* __restrict__ vt, bf16* __restrict__ aout)
{
  __shared__ bf16 sK[64 * 136];    // [k][d], +8 pad
  __shared__ bf16 sV[128 * 72];    // [d][k], +8 pad
  __shared__ bf16 sP[128 * 72];    // [q][k]: rows 0-63 lo tile, 64-127 hi
  const int t = threadIdx.x;
  const int lane = t & 63, w = t >> 6;
  const int lr = lane & 15, lq = lane >> 4;
  const int p  = blockIdx.x & 15;
  const int bh = blockIdx.x >> 4;
  const int bb = bh >> 4, h = bh & 15;
  const int qlo = p, qhi = 31 - p;

  bf16x8 aqL[4], aqH[4];
  {
    const bf16* qpL =
        qb + ((size_t)bh * SEQ + qlo * 64 + w * 16 + lr) * DHEAD + lq * 8;
    const bf16* qpH =
        qb + ((size_t)bh * SEQ + qhi * 64 + w * 16 + lr) * DHEAD + lq * 8;
#pragma unroll
    for (int ks = 0; ks < 4; ++ks) {
      aqL[ks] = *(const bf16x8*)(qpL + ks * 32);
      aqH[ks] = *(const bf16x8*)(qpH + ks * 32);
    }
  }

  f32x4 oL[8], oH[8];
#pragma unroll
  for (int i = 0; i < 8; ++i) {
    oL[i] = (f32x4){0.f, 0.f, 0.f, 0.f};
    oH[i] = (f32x4){0.f, 0.f, 0.f, 0.f};
  }
  float mL[4] = {NEG_BIG, NEG_BIG, NEG_BIG, NEG_BIG};
  float mH[4] = {NEG_BIG, NEG_BIG, NEG_BIG, NEG_BIG};
  float lL[4] = {0.f, 0.f, 0.f, 0.f};
  float lH[4] = {0.f, 0.f, 0.f, 0.f};

  bf16x8 rk[4], rv[4];
  const int kr_ = t >> 4, kd_ = t & 15;
  const int vr_ = t >> 3, vk_ = t & 7;
#define FETCH(ktv)                                                          \
  {                                                                         \
    const int _kt = (ktv);                                                  \
    _Pragma("unroll") for (int i = 0; i < 4; ++i) {                         \
      rk[i] = *(const bf16x8*)(kb + ((size_t)bh * SEQ + _kt * 64 +          \
                                     (i * 16 + kr_)) * DHEAD + kd_ * 8);    \
      rv[i] = *(const bf16x8*)(vt + ((size_t)bh * DHEAD + (i * 32 + vr_)) * \
                                     SEQ + _kt * 64 + vk_ * 8);             \
    }                                                                       \
  }
#define COMMIT()                                                            \
  {                                                                         \
    _Pragma("unroll") for (int i = 0; i < 4; ++i) {                         \
      *(bf16x8*)(sK + (i * 16 + kr_) * 136 + kd_ * 8) = rk[i];              \
      *(bf16x8*)(sV + (i * 32 + vr_) * 72 + vk_ * 8) = rv[i];               \
    }                                                                       \
  }

  FETCH(0);
  COMMIT();
  __syncthreads();

  for (int kt = 0; kt <= qhi; ++kt) {
    if (kt < qhi) FETCH(kt + 1);
    const bool doLo = (kt <= qlo);

    qk_softmax_tile(sK, sP, aqH, mH, lH, oH, kt, qhi, w, lr, lq, 64);
    if (doLo) qk_softmax_tile(sK, sP, aqL, mL, lL, oL, kt, qlo, w, lr, lq, 0);
    // sP is wave-private: wave-level LDS drain suffices
    asm volatile("s_waitcnt lgkmcnt(0)" ::: "memory");
    pv_tile(sP, sV, oH, w, lr, lq, 64);
    if (doLo) pv_tile(sP, sV, oL, w, lr, lq, 0);

    __syncthreads();
    if (kt < qhi) {
      COMMIT();
      __syncthreads();
    }
  }

#pragma unroll
  for (int side = 0; side < 2; ++side) {
    const f32x4* oacc = side ? oH : oL;
    const float* l_i = side ? lH : lL;
    const int qt = side ? qhi : qlo;
    float inv[4];
#pragma unroll
    for (int reg = 0; reg < 4; ++reg) inv[reg] = 1.0f / l_i[reg];
#pragma unroll
    for (int dt = 0; dt < 8; ++dt)
#pragma unroll
      for (int reg = 0; reg < 4; ++reg) {
        const int qg = qt * 64 + w * 16 + lq * 4 + reg;
        aout[((size_t)bb * SEQ + qg) * EMBED + h * 128 + dt * 16 + lr] =
            (bf16)(oacc[dt][reg] * inv[reg]);
      }
  }
#undef FETCH
#undef COMMIT
}

extern "C" void kernel_launch(void* const* d_in, const int* in_sizes, int n_in,
                              void* d_out, int out_size, void* d_ws, size_t ws_size,
                              hipStream_t stream) {
  const void* x    = d_in[0];
  const void* Wqkv = d_in[1];
  const void* bqkv = d_in[2];
  const void* Wout = d_in[3];
  const void* bout = d_in[4];

  int* flagp = (int*)d_ws;
  bf16* base = (bf16*)((char*)d_ws + 256);
  bf16* xb   = base;
  bf16* w1b  = xb + NX;
  bf16* b1b  = w1b + NW1;
  bf16* w2b  = b1b + NB1;
  bf16* b2b  = w2b + NW2;
  bf16* qb   = b2b + NB2;
  bf16* kb   = qb + NX;
  bf16* vt   = kb + NX;
  bf16* aout = vt + NX;

  dim3 blk(256);
  convert_inputs<<<dim3(1024), blk, 0, stream>>>(
      x, Wqkv, bqkv, Wout, bout, xb, w1b, b1b, w2b, b2b, flagp);
  // QKV projection: M=4096, N=6144, K=2048
  gemm_nt<0><<<dim3(48, 32), blk, 0, stream>>>(xb, w1b, b1b, EMBED,
                                               (void*)qb, kb, vt, flagp);
  // attention: 32 bh * 16 balanced pairs
  attn_fwd<<<dim3(512), blk, 0, stream>>>(qb, kb, vt, aout);
  // out projection: M=4096, N=2048, K=2048
  gemm_nt<1><<<dim3(16, 32), blk, 0, stream>>>(aout, w2b, b2b, EMBED,
                                               d_out, nullptr, nullptr, flagp);
}